// Round 1
// baseline (6180.865 us; speedup 1.0000x reference)
//
#include <hip/hip_runtime.h>
#include <math.h>

#define WIDTH 256
#define PTS 8
#define ROWS 48          // 6 * PTS (rows: point*6 + {z, zx, zy, zt, zxx, zyy})
#define LSTR 52          // padded LDS row stride in floats (multiple of 4 for b64/b128 alignment)

__global__ __launch_bounds__(256, 3)
void pde_net_kernel(const float* __restrict__ xyt,
                    const float* __restrict__ w0, const float* __restrict__ b0,
                    const float* __restrict__ w1, const float* __restrict__ b1,
                    const float* __restrict__ w2, const float* __restrict__ b2,
                    const float* __restrict__ w3, const float* __restrict__ b3,
                    const float* __restrict__ w4, const float* __restrict__ b4,
                    const float* __restrict__ w5, const float* __restrict__ b5,
                    const float* __restrict__ w6, const float* __restrict__ b6,
                    float* __restrict__ out)
{
    // Z is feature-major: Z[j * LSTR + r], r = point*6 + vec. 256*52*4 = 53248 B.
    __shared__ float Z[WIDTH * LSTR];
    __shared__ float red[4 * ROWS];
    __shared__ float dvals[ROWS];
    __shared__ float pxyt[PTS * 3];

    const int tid = threadIdx.x;
    const int cg  = tid >> 3;      // 0..31 column group
    const int g   = tid & 7;       // 0..7  point-in-tile / row group
    const int c0  = cg * 8;
    const int r0  = g * 6;
    const long gp0 = (long)blockIdx.x * PTS;

    if (tid < PTS * 3) pxyt[tid] = xyt[gp0 * 3 + tid];
    __syncthreads();

    // ---------------- layer 0: (3 -> 256) affine + tanh, 2nd-order forward mode ----
    {
        const float x = pxyt[g * 3 + 0];
        const float y = pxyt[g * 3 + 1];
        const float t = pxyt[g * 3 + 2];
        #pragma unroll
        for (int c = 0; c < 8; ++c) {
            const int j = c0 + c;
            const float wx = w0[0 * WIDTH + j];
            const float wy = w0[1 * WIDTH + j];
            const float wt = w0[2 * WIDTH + j];
            const float uz = fmaf(x, wx, fmaf(y, wy, fmaf(t, wt, b0[j])));
            const float zv = tanhf(uz);
            const float s  = 1.0f - zv * zv;
            float* zp = &Z[j * LSTR + r0];
            zp[0] = zv;                       // value
            zp[1] = s * wx;                   // d/dx
            zp[2] = s * wy;                   // d/dy
            zp[3] = s * wt;                   // d/dt
            zp[4] = -2.0f * zv * s * wx * wx; // d2/dx2 (u''=0)
            zp[5] = -2.0f * zv * s * wy * wy; // d2/dy2
        }
    }
    __syncthreads();

    // ---------------- hidden layers 1..5: (256 -> 256) affine + tanh ----------------
    const float* Ws[5] = { w1, w2, w3, w4, w5 };
    const float* Bs[5] = { b1, b2, b3, b4, b5 };

    for (int l = 0; l < 5; ++l) {
        const float* __restrict__ W = Ws[l];
        const float* __restrict__ B = Bs[l];

        float acc[6][8];
        #pragma unroll
        for (int v = 0; v < 6; ++v)
            #pragma unroll
            for (int c = 0; c < 8; ++c) acc[v][c] = 0.0f;

        #pragma unroll 4
        for (int k = 0; k < WIDTH; ++k) {
            const float2 a01 = *(const float2*)&Z[k * LSTR + r0 + 0];
            const float2 a23 = *(const float2*)&Z[k * LSTR + r0 + 2];
            const float2 a45 = *(const float2*)&Z[k * LSTR + r0 + 4];
            const float4 wA  = *(const float4*)&W[k * WIDTH + c0 + 0];
            const float4 wB  = *(const float4*)&W[k * WIDTH + c0 + 4];
            const float a[6]  = { a01.x, a01.y, a23.x, a23.y, a45.x, a45.y };
            const float wv[8] = { wA.x, wA.y, wA.z, wA.w, wB.x, wB.y, wB.z, wB.w };
            #pragma unroll
            for (int v = 0; v < 6; ++v)
                #pragma unroll
                for (int c = 0; c < 8; ++c)
                    acc[v][c] = fmaf(a[v], wv[c], acc[v][c]);
        }
        __syncthreads();   // all reads of Z done before overwrite

        #pragma unroll
        for (int c = 0; c < 8; ++c) {
            const int j = c0 + c;
            const float uz = acc[0][c] + B[j];
            const float zv = tanhf(uz);
            const float s  = 1.0f - zv * zv;
            const float m2 = -2.0f * zv * s;
            float* zp = &Z[j * LSTR + r0];
            zp[0] = zv;
            zp[1] = s * acc[1][c];
            zp[2] = s * acc[2][c];
            zp[3] = s * acc[3][c];
            zp[4] = fmaf(m2 * acc[1][c], acc[1][c], s * acc[4][c]);
            zp[5] = fmaf(m2 * acc[2][c], acc[2][c], s * acc[5][c]);
        }
        __syncthreads();
    }

    // ---------------- final layer: (256 -> 1) dot products ----------------
    {
        const int r = tid & 63;
        const int chunk = tid >> 6;   // 0..3, 64 features each
        if (r < ROWS) {
            float partial = 0.0f;
            const int f0 = chunk * 64;
            #pragma unroll 8
            for (int f = 0; f < 64; ++f)
                partial = fmaf(Z[(f0 + f) * LSTR + r], w6[f0 + f], partial);
            red[chunk * ROWS + r] = partial;
        }
    }
    __syncthreads();
    if (tid < ROWS) {
        dvals[tid] = red[tid] + red[ROWS + tid] + red[2 * ROWS + tid] + red[3 * ROWS + tid];
    }
    __syncthreads();

    // ---------------- residual ----------------
    if (tid < PTS) {
        const int p = tid;
        const float h   = dvals[6 * p + 0] + b6[0];
        const float hx  = dvals[6 * p + 1];
        const float hy  = dvals[6 * p + 2];
        const float ht  = dvals[6 * p + 3];
        const float hxx = dvals[6 * p + 4];
        const float hyy = dvals[6 * p + 5];
        const float x = pxyt[p * 3 + 0];
        const float y = pxyt[p * 3 + 1];
        const float t = pxyt[p * 3 + 2];
        const float pi = 3.14159265358979323846f;
        const float f = sinf(pi * x) * sinf(pi * y) * expf(-t);
        // res = MU*ht - K*(h*(hxx+hyy) + hx^2 + hy^2) - f, MU=1, K=0.5
        const float res = ht - 0.5f * (h * (hxx + hyy) + hx * hx + hy * hy) - f;
        out[gp0 + p] = res;
    }
}

extern "C" void kernel_launch(void* const* d_in, const int* in_sizes, int n_in,
                              void* d_out, int out_size, void* d_ws, size_t ws_size,
                              hipStream_t stream) {
    const float* xyt = (const float*)d_in[0];
    const float* w0  = (const float*)d_in[1];
    const float* b0  = (const float*)d_in[2];
    const float* w1  = (const float*)d_in[3];
    const float* b1  = (const float*)d_in[4];
    const float* w2  = (const float*)d_in[5];
    const float* b2  = (const float*)d_in[6];
    const float* w3  = (const float*)d_in[7];
    const float* b3  = (const float*)d_in[8];
    const float* w4  = (const float*)d_in[9];
    const float* b4  = (const float*)d_in[10];
    const float* w5  = (const float*)d_in[11];
    const float* b5  = (const float*)d_in[12];
    const float* w6  = (const float*)d_in[13];
    const float* b6  = (const float*)d_in[14];
    float* out = (float*)d_out;

    const int npts = in_sizes[0] / 3;   // 131072
    dim3 grid(npts / PTS);
    dim3 block(256);
    pde_net_kernel<<<grid, block, 0, stream>>>(xyt, w0, b0, w1, b1, w2, b2,
                                               w3, b3, w4, b4, w5, b5, w6, b6, out);
}